// Round 8
// baseline (239.663 us; speedup 1.0000x reference)
//
#include <hip/hip_runtime.h>
#include <hip/hip_bf16.h>

// e3nn FullyConnectedTensorProduct (128x0e+128x1o)^2 -> 128x0e+128x1o, N=4096
// R8: 2 row-tiles/wave (32n x 32w) -> halves per-FLOP LDS-B traffic and VALU;
//     native _Float16x2 A-gen (regalloc writes pk results straight into MFMA
//     tuples); 4-wave WGs, 2 WG/CU; counted-vmcnt 4-buffer weight pipeline.
// ws layout: [WT f16 20MB][X1g f16 4MB][X2g f16 4MB]

typedef _Float16 f16;
typedef _Float16 f16x8 __attribute__((ext_vector_type(8)));
typedef _Float16 h2 __attribute__((ext_vector_type(2)));
typedef float f32x4 __attribute__((ext_vector_type(4)));
typedef unsigned u32;

#define WT_BYTES  (5u*4u*128u*4096u*2u)     // 20971520 B = 16 slices x 655360 el x 2B
#define X1_BYTES  (32u*4u*16384u*2u)        // 4194304  ([tile32][usec4][u32][n128][q4] f16)
#define SLICE_EL  655360u                    // elems per slice = 128 chunks x 5120
#define CHUNK_EL  5120u                      // elems per K-chunk (10 KB)

__device__ __forceinline__ h2 bc(u32 x){ union{u32 u; h2 h;} c; c.u=x; return c.h; }

union F8 { h2 h[4]; f16x8 v; };

__device__ __forceinline__ void gl_lds16(const f16* g, f16* l) {
    __builtin_amdgcn_global_load_lds(
        (const __attribute__((address_space(1))) void*)g,
        (__attribute__((address_space(3))) void*)l,
        16, 0, 0);
}

// ---- prologue: weights f32 [u][v][w] -> WT[slice][c][p][32w][4q-swz][8v] f16 ----
__global__ __launch_bounds__(256) void pack_w_kernel(
    const float* __restrict__ w0, const float* __restrict__ w1,
    const float* __restrict__ w2, const float* __restrict__ w3,
    const float* __restrict__ w4, f16* __restrict__ wt)
{
    __shared__ float tl[64][130];
    const int b = blockIdx.x;           // 640 = 5 paths x 128 u
    const int p = b >> 7;
    const int u = b & 127;
    const int usec = u >> 5;
    const int uin  = u & 31;
    const float* src = (p==0)?w0:(p==1)?w1:(p==2)?w2:(p==3)?w3:w4;
    const float scale = (p==0)?1.0f:(p==4)?0.40824829046386302f:0.57735026918962576f;

    for (int h = 0; h < 2; ++h) {       // two 64-v halves
        const float* spR = src + (size_t)u*16384 + (size_t)h*8192;
        #pragma unroll
        for (int k = 0; k < 8; ++k) {
            const int e4 = (k*256 + threadIdx.x) * 4;
            const float4 v4 = *(const float4*)(spR + e4);
            const int vi = e4 >> 7, w = e4 & 127;
            tl[vi][w+0]=v4.x; tl[vi][w+1]=v4.y; tl[vi][w+2]=v4.z; tl[vi][w+3]=v4.w;
        }
        __syncthreads();
        #pragma unroll
        for (int k = 0; k < 4; ++k) {
            const int cid = k*256 + threadIdx.x;     // 0..1023 16B-chunks
            const int vbh  = cid >> 9;
            const int wsec = (cid >> 7) & 3;
            const int w    = (cid >> 2) & 31;
            const int q    = cid & 3;
            const int vb   = h*2 + vbh;
            const int c    = vb*32 + uin;
            const int qs   = q ^ ((w >> 1) & 3);
            f16x8 t8;
            #pragma unroll
            for (int j = 0; j < 8; ++j)
                t8[j] = (f16)(tl[vbh*32 + q*8 + j][wsec*32 + w] * scale);
            *(f16x8*)(wt + (size_t)(usec*4 + wsec)*SLICE_EL + (size_t)c*CHUNK_EL
                          + p*1024 + w*32 + qs*8) = t8;
        }
        __syncthreads();
    }
}

// ---- prologue: pack x1 -> [tile32][usec][u32][n128][q4]; x2 -> [n][q][v] f16 ----
__global__ __launch_bounds__(256) void pack_x_kernel(
    const float* __restrict__ x1s, const float* __restrict__ x1v,
    const float* __restrict__ x2s, const float* __restrict__ x2v,
    f16* __restrict__ x1g, f16* __restrict__ x2g)
{
    if (blockIdx.x < 128) {
        __shared__ uint2 tl[128][33];
        const int nb = blockIdx.x;      // 32-node block
        #pragma unroll
        for (int k = 0; k < 16; ++k) {
            const int idx = k*256 + threadIdx.x;    // u fast
            const int u = idx & 127, nd = idx >> 7;
            const size_t i = (size_t)(nb*32 + nd)*128 + u;
            union { f16 h[4]; uint2 u2; } tp;
            tp.h[0] = (f16)x1s[i];
            tp.h[1] = (f16)x1v[i*3 + 0];
            tp.h[2] = (f16)x1v[i*3 + 1];
            tp.h[3] = (f16)x1v[i*3 + 2];
            tl[u][nd] = tp.u2;
        }
        __syncthreads();
        uint2* og = (uint2*)x1g;
        const int t = nb >> 2, nd0 = (nb & 3) * 32;   // tile of 128 nodes
        #pragma unroll
        for (int k = 0; k < 16; ++k) {
            const int idx = k*256 + threadIdx.x;    // nd fast
            const int u = idx >> 5, nd = idx & 31;
            og[(((t*4 + (u>>5))*32 + (u&31)) << 7) + nd0 + nd] = tl[u][nd];
        }
    } else {
        const int tt = (blockIdx.x - 128)*256 + threadIdx.x;
        const int n = tt >> 7, v = tt & 127;
        const size_t b = (size_t)n*512;
        const size_t i = (size_t)n*128 + v;
        x2g[b +   0 + v] = (f16)x2s[i];
        x2g[b + 128 + v] = (f16)x2v[i*3 + 0];
        x2g[b + 256 + v] = (f16)x2v[i*3 + 1];
        x2g[b + 384 + v] = (f16)x2v[i*3 + 2];
    }
}

// ---- main: 512 WGs = 32 node-tiles(128) x 4 u-sec x 4 w-sec, 256 thr ----
// XCD-pinned slices: b&7 = XCD hosts slices {2x,2x+1} (2.5MB, L2-resident).
// wave = 32 nodes (2 rt) x 32 w. 2 WG/CU. 4-buf weight pipeline: stage c+2
// at body c; counted vmcnt (never 0 mid-loop) + raw s_barrier.
__global__ __launch_bounds__(256, 2) void tp_main(
    const f16* __restrict__ wt, const f16* __restrict__ x1g,
    const f16* __restrict__ x2g, float* __restrict__ out)
{
    __shared__ __align__(16) f16 wlds[4*CHUNK_EL];  // 40 KB quad-buffer weights
    __shared__ __align__(16) f16 x1lds[16384];      // 32 KB x1 slice [u32][n128][q4]

    const int tid  = threadIdx.x;
    const int lane = tid & 63;
    const int wv   = tid >> 6;       // 0..3
    const int kg   = lane >> 4;
    const int lr   = lane & 15;

    const int b    = blockIdx.x;
    const int s    = (b & 7)*2 + ((b >> 3) & 1);  // weight slice 0..15 (XCD-pinned)
    const int t    = b >> 4;                      // node tile 0..31
    const int usec = s >> 2;
    const int wsec = s & 3;

    const f16* wstream = wt + (size_t)s * SLICE_EL;

    int boff[2];
    #pragma unroll
    for (int ct = 0; ct < 2; ++ct) {
        const int wp = ct*16 + lr;
        boff[ct] = wp*32 + ((kg ^ ((wp >> 1) & 3)) * 8);
    }

    // prologue: x1 slice (32KB, 8 loads/thread) + weight chunks 0,1; drain once
    {
        const f16* src = x1g + ((size_t)(t*4 + usec) << 14);
        #pragma unroll
        for (int r = 0; r < 8; ++r)
            gl_lds16(src + r*2048 + tid*8, x1lds + r*2048 + wv*512 + lane*8);
    }
    #pragma unroll
    for (int k = 0; k < 2; ++k) {   // chunk k: wave wv covers elems wv*1280..+1280
        const f16* sc = wstream + k*CHUNK_EL + wv*1280 + lane*8;
        f16* dc = wlds + k*CHUNK_EL + wv*1280;
        gl_lds16(sc, dc);
        gl_lds16(sc + 512, dc + 512);
        if (lane < 32) gl_lds16(sc + 1024, dc + 1024);
    }
    __syncthreads();   // full drain (prologue only)

    f32x4 acc[2][2][4];
    #pragma unroll
    for (int rt = 0; rt < 2; ++rt)
        #pragma unroll
        for (int c2 = 0; c2 < 2; ++c2)
            #pragma unroll
            for (int d = 0; d < 4; ++d)
                acc[rt][c2][d] = (f32x4){0.f, 0.f, 0.f, 0.f};

    h2 xq[2][4][4];   // [rt][q][k-pair] packed f16 pairs (32 VGPR)
    const f16* wsrc = wstream + 2*CHUNK_EL + wv*1280 + lane*8;

    for (int vb = 0; vb < 4; ++vb) {
        // issue x2 refresh for this v-block (8 dwordx4; drained at first body)
        #pragma unroll
        for (int rt = 0; rt < 2; ++rt) {
            const int n = t*128 + wv*32 + rt*16 + lr;
            const f16* xb = x2g + ((size_t)n << 9) + kg*8 + vb*32;
            #pragma unroll
            for (int q = 0; q < 4; ++q) {
                const uint4 h = *(const uint4*)(xb + (q << 7));
                xq[rt][q][0] = bc(h.x); xq[rt][q][1] = bc(h.y);
                xq[rt][q][2] = bc(h.z); xq[rt][q][3] = bc(h.w);
            }
        }
        for (int u2b = 0; u2b < 32; u2b += 4) {
            #pragma unroll
            for (int uu = 0; uu < 4; ++uu) {       // LDS buffer index (static)
                const int u2 = u2b + uu;
                const int c  = vb*32 + u2;

                // stage chunk c+2 into buf[(uu+2)&3]: 3 loads/wave (3rd masked)
                if (c < 126) {
                    f16* dc = wlds + ((uu + 2) & 3)*CHUNK_EL + wv*1280;
                    gl_lds16(wsrc, dc);
                    gl_lds16(wsrc + 512, dc + 512);
                    if (lane < 32) gl_lds16(wsrc + 1024, dc + 1024);
                }
                wsrc += CHUNK_EL;

                // counted waits: keep chunks c+1,c+2 in flight; drain x2 at vb top
                if (u2 == 0 || c == 126) { asm volatile("s_waitcnt vmcnt(3)" ::: "memory"); }
                else if (c == 127)       { asm volatile("s_waitcnt vmcnt(0)" ::: "memory"); }
                else                     { asm volatile("s_waitcnt vmcnt(6)" ::: "memory"); }
                __builtin_amdgcn_s_barrier();
                __builtin_amdgcn_sched_barrier(0);

                // B fragments (5 paths x 2 col-tiles) from buf[uu]
                f16x8 bfr[5][2];
                const f16* wb = wlds + uu*CHUNK_EL;
                #pragma unroll
                for (int p = 0; p < 5; ++p)
                    #pragma unroll
                    for (int ct = 0; ct < 2; ++ct)
                        bfr[p][ct] = *(const f16x8*)(wb + p*1024 + boff[ct]);

                #pragma unroll
                for (int rt = 0; rt < 2; ++rt) {
                    // x1 broadcasts (packed f16 pairs via v_perm)
                    const uint2 h1 = *(const uint2*)(x1lds + u2*512 + (wv*32 + rt*16 + lr)*4);
                    const h2 ps1 = bc(__builtin_amdgcn_perm(h1.x, h1.x, 0x01000100u));
                    h2 pv[3];
                    pv[0] = bc(__builtin_amdgcn_perm(h1.x, h1.x, 0x03020302u));
                    pv[1] = bc(__builtin_amdgcn_perm(h1.y, h1.y, 0x01000100u));
                    pv[2] = bc(__builtin_amdgcn_perm(h1.y, h1.y, 0x03020302u));

                    // ---- scalar-output channels: sss, vvs ----
                    {
                        F8 f0, f1;
                        #pragma unroll
                        for (int j = 0; j < 4; ++j) {
                            f0.h[j] = ps1 * xq[rt][0][j];
                            h2 d = pv[0] * xq[rt][1][j];
                            d = __builtin_elementwise_fma(pv[1], xq[rt][2][j], d);
                            f1.h[j] = __builtin_elementwise_fma(pv[2], xq[rt][3][j], d);
                        }
                        #pragma unroll
                        for (int ct = 0; ct < 2; ++ct) {
                            acc[rt][ct][0] = __builtin_amdgcn_mfma_f32_16x16x32_f16(f0.v, bfr[0][ct], acc[rt][ct][0], 0,0,0);
                            acc[rt][ct][0] = __builtin_amdgcn_mfma_f32_16x16x32_f16(f1.v, bfr[1][ct], acc[rt][ct][0], 0,0,0);
                        }
                    }
                    // ---- vector-output channels per k: svv, vsv, vvv(cross) ----
                    #pragma unroll
                    for (int k = 0; k < 3; ++k) {
                        const int k1 = (k+1) % 3, k2 = (k+2) % 3;
                        F8 fa, fb, fc;
                        #pragma unroll
                        for (int j = 0; j < 4; ++j) {
                            fa.h[j] = ps1   * xq[rt][1+k][j];
                            fb.h[j] = pv[k] * xq[rt][0][j];
                            h2 tx = pv[k1] * xq[rt][1+k2][j];
                            fc.h[j] = __builtin_elementwise_fma(-pv[k2], xq[rt][1+k1][j], tx);
                        }
                        #pragma unroll
                        for (int ct = 0; ct < 2; ++ct) {
                            acc[rt][ct][1+k] = __builtin_amdgcn_mfma_f32_16x16x32_f16(fa.v, bfr[2][ct], acc[rt][ct][1+k], 0,0,0);
                            acc[rt][ct][1+k] = __builtin_amdgcn_mfma_f32_16x16x32_f16(fb.v, bfr[3][ct], acc[rt][ct][1+k], 0,0,0);
                            acc[rt][ct][1+k] = __builtin_amdgcn_mfma_f32_16x16x32_f16(fc.v, bfr[4][ct], acc[rt][ct][1+k], 0,0,0);
                        }
                    }
                }
            }
        }
    }

    // epilogue: accumulate u-section partials into d_out
    #pragma unroll
    for (int rt = 0; rt < 2; ++rt) {
        #pragma unroll
        for (int ct = 0; ct < 2; ++ct) {
            const int w = wsec*32 + ct*16 + lr;
            #pragma unroll
            for (int j = 0; j < 4; ++j) {
                const int n = t*128 + wv*32 + rt*16 + kg*4 + j;
                float* op = out + (size_t)n*512;
                unsafeAtomicAdd(op + w,             acc[rt][ct][0][j]);
                unsafeAtomicAdd(op + 128 + w*3 + 0, acc[rt][ct][1][j]);
                unsafeAtomicAdd(op + 128 + w*3 + 1, acc[rt][ct][2][j]);
                unsafeAtomicAdd(op + 128 + w*3 + 2, acc[rt][ct][3][j]);
            }
        }
    }
}

extern "C" void kernel_launch(void* const* d_in, const int* in_sizes, int n_in,
                              void* d_out, int out_size, void* d_ws, size_t ws_size,
                              hipStream_t stream)
{
    const float* x1s = (const float*)d_in[0];
    const float* x1v = (const float*)d_in[1];
    const float* x2s = (const float*)d_in[2];
    const float* x2v = (const float*)d_in[3];
    const float* w0  = (const float*)d_in[4];
    const float* w1  = (const float*)d_in[5];
    const float* w2  = (const float*)d_in[6];
    const float* w3  = (const float*)d_in[7];
    const float* w4  = (const float*)d_in[8];

    f16* wtb = (f16*)d_ws;
    f16* x1g = (f16*)((char*)d_ws + WT_BYTES);
    f16* x2g = (f16*)((char*)d_ws + WT_BYTES + X1_BYTES);
    float* out = (float*)d_out;

    pack_w_kernel<<<640, 256, 0, stream>>>(w0, w1, w2, w3, w4, wtb);
    pack_x_kernel<<<2176, 256, 0, stream>>>(x1s, x1v, x2s, x2v, x1g, x2g);
    hipMemsetAsync(d_out, 0, (size_t)out_size*sizeof(float), stream);
    tp_main<<<512, 256, 0, stream>>>(wtb, x1g, x2g, out);
}

// Round 9
// 234.054 us; speedup vs baseline: 1.0240x; 1.0240x over previous
//
#include <hip/hip_runtime.h>
#include <hip/hip_bf16.h>

// e3nn FullyConnectedTensorProduct (128x0e+128x1o)^2 -> 128x0e+128x1o, N=4096
// R9: wave = 16n x 64w (1rt x 4ct) -> A-gen redundancy 4x -> 2x (VALU halves);
//     8 slices (usec x whalf) of 2.5MB, one per XCD; 2-buffer stage-after-
//     barrier pipeline (vmcnt(0) hidden under full body).
// ws layout: [WT f16 20MB][X1g f16 4MB][X2g f16 4MB]

typedef _Float16 f16;
typedef _Float16 f16x8 __attribute__((ext_vector_type(8)));
typedef _Float16 h2 __attribute__((ext_vector_type(2)));
typedef float f32x4 __attribute__((ext_vector_type(4)));
typedef unsigned u32;

#define WT_BYTES  (5u*4u*128u*4096u*2u)     // 20971520 B = 8 slices x 1310720 el x 2B
#define X1_BYTES  (64u*4u*8192u*2u)         // 4194304  ([tile64][usec4][u32][n64][q4] f16)
#define SLICE_EL  1310720u                   // elems per slice = 128 chunks x 10240
#define CHUNK_EL  10240u                     // elems per K-chunk (20 KB): [p5][64w][4q][8v]

__device__ __forceinline__ h2 bc(u32 x){ union{u32 u; h2 h;} c; c.u=x; return c.h; }

union F8 { h2 h[4]; f16x8 v; };

__device__ __forceinline__ void gl_lds16(const f16* g, f16* l) {
    __builtin_amdgcn_global_load_lds(
        (const __attribute__((address_space(1))) void*)g,
        (__attribute__((address_space(3))) void*)l,
        16, 0, 0);
}

// ---- prologue: weights f32 [u][v][w] -> WT[slice][c][p][64w][4q-swz][8v] f16 ----
__global__ __launch_bounds__(256) void pack_w_kernel(
    const float* __restrict__ w0, const float* __restrict__ w1,
    const float* __restrict__ w2, const float* __restrict__ w3,
    const float* __restrict__ w4, f16* __restrict__ wt)
{
    __shared__ float tl[64][130];
    const int b = blockIdx.x;           // 640 = 5 paths x 128 u
    const int p = b >> 7;
    const int u = b & 127;
    const int usec = u >> 5;
    const int uin  = u & 31;
    const float* src = (p==0)?w0:(p==1)?w1:(p==2)?w2:(p==3)?w3:w4;
    const float scale = (p==0)?1.0f:(p==4)?0.40824829046386302f:0.57735026918962576f;

    for (int h = 0; h < 2; ++h) {       // two 64-v halves
        const float* spR = src + (size_t)u*16384 + (size_t)h*8192;
        #pragma unroll
        for (int k = 0; k < 8; ++k) {
            const int e4 = (k*256 + threadIdx.x) * 4;
            const float4 v4 = *(const float4*)(spR + e4);
            const int vi = e4 >> 7, w = e4 & 127;
            tl[vi][w+0]=v4.x; tl[vi][w+1]=v4.y; tl[vi][w+2]=v4.z; tl[vi][w+3]=v4.w;
        }
        __syncthreads();
        #pragma unroll
        for (int k = 0; k < 4; ++k) {
            const int cid = k*256 + threadIdx.x;     // 0..1023 16B-chunks
            const int q     = cid & 3;
            const int wg    = (cid >> 2) & 127;      // global w
            const int vbh   = cid >> 9;
            const int vb    = h*2 + vbh;
            const int c     = vb*32 + uin;
            const int whalf = wg >> 6;
            const int wl    = wg & 63;
            const int qs    = q ^ ((wl >> 1) & 3);
            f16x8 t8;
            #pragma unroll
            for (int j = 0; j < 8; ++j)
                t8[j] = (f16)(tl[vbh*32 + q*8 + j][wg] * scale);
            *(f16x8*)(wt + (size_t)(usec*2 + whalf)*SLICE_EL + (size_t)c*CHUNK_EL
                          + p*2048 + wl*32 + qs*8) = t8;
        }
        __syncthreads();
    }
}

// ---- prologue: pack x1 -> [tile64][usec][u32][n64][q4]; x2 -> [n][q][v] f16 ----
__global__ __launch_bounds__(256) void pack_x_kernel(
    const float* __restrict__ x1s, const float* __restrict__ x1v,
    const float* __restrict__ x2s, const float* __restrict__ x2v,
    f16* __restrict__ x1g, f16* __restrict__ x2g)
{
    if (blockIdx.x < 128) {
        __shared__ uint2 tl[128][33];
        const int nb = blockIdx.x;      // 32-node block
        #pragma unroll
        for (int k = 0; k < 16; ++k) {
            const int idx = k*256 + threadIdx.x;    // u fast
            const int u = idx & 127, nd = idx >> 7;
            const size_t i = (size_t)(nb*32 + nd)*128 + u;
            union { f16 h[4]; uint2 u2; } tp;
            tp.h[0] = (f16)x1s[i];
            tp.h[1] = (f16)x1v[i*3 + 0];
            tp.h[2] = (f16)x1v[i*3 + 1];
            tp.h[3] = (f16)x1v[i*3 + 2];
            tl[u][nd] = tp.u2;
        }
        __syncthreads();
        uint2* og = (uint2*)x1g;
        const int t = nb >> 1, nd0 = (nb & 1) * 32;   // tile of 64 nodes
        #pragma unroll
        for (int k = 0; k < 16; ++k) {
            const int idx = k*256 + threadIdx.x;    // nd fast
            const int u = idx >> 5, nd = idx & 31;
            og[(((t*4 + (u>>5))*32 + (u&31)) << 6) + nd0 + nd] = tl[u][nd];
        }
    } else {
        const int tt = (blockIdx.x - 128)*256 + threadIdx.x;
        const int n = tt >> 7, v = tt & 127;
        const size_t b = (size_t)n*512;
        const size_t i = (size_t)n*128 + v;
        x2g[b +   0 + v] = (f16)x2s[i];
        x2g[b + 128 + v] = (f16)x2v[i*3 + 0];
        x2g[b + 256 + v] = (f16)x2v[i*3 + 1];
        x2g[b + 384 + v] = (f16)x2v[i*3 + 2];
    }
}

// ---- main: 512 WGs = 64 node-tiles(64) x 8 slices(usec x whalf), 256 thr ----
// slice b&7 pinned to XCD b&7 (2.5MB, L2-resident). wave = 16n x 64w (4 ct).
// 2 WG/CU. 2-buffer pipeline: body c = vmcnt(0); barrier; stage c+1; compute c.
__global__ __launch_bounds__(256, 2) void tp_main(
    const f16* __restrict__ wt, const f16* __restrict__ x1g,
    const f16* __restrict__ x2g, float* __restrict__ out)
{
    __shared__ __align__(16) f16 wlds[2*CHUNK_EL];  // 40 KB double-buffer weights
    __shared__ __align__(16) f16 x1lds[8192];       // 16 KB x1 slice [u32][n64][q4]

    const int tid  = threadIdx.x;
    const int lane = tid & 63;
    const int wv   = tid >> 6;       // 0..3
    const int kg   = lane >> 4;
    const int lr   = lane & 15;

    const int b     = blockIdx.x;
    const int slice = b & 7;                      // usec*2 + whalf, XCD-pinned
    const int t     = b >> 3;                     // node tile 0..63
    const int usec  = slice >> 1;
    const int whalf = slice & 1;

    const f16* wstream = wt + (size_t)slice * SLICE_EL;

    int boff[4];
    #pragma unroll
    for (int ct = 0; ct < 4; ++ct) {
        const int wp = ct*16 + lr;                // w row within 64-tile
        boff[ct] = wp*32 + ((kg ^ ((wp >> 1) & 3)) * 8);
    }

    // prologue: x1 slice (16KB) + weight chunk 0 (no sync; body 0 barrier covers)
    {
        const f16* src = x1g + ((size_t)(t*4 + usec) << 13);
        #pragma unroll
        for (int r = 0; r < 4; ++r)
            gl_lds16(src + r*2048 + wv*512 + lane*8, x1lds + r*2048 + wv*512 + lane*8);
    }
    #pragma unroll
    for (int r = 0; r < 5; ++r)
        gl_lds16(wstream + r*2048 + wv*512 + lane*8, wlds + r*2048 + wv*512 + lane*8);

    f32x4 acc[4][4];   // [ct][channel]
    #pragma unroll
    for (int c2 = 0; c2 < 4; ++c2)
        #pragma unroll
        for (int d = 0; d < 4; ++d)
            acc[c2][d] = (f32x4){0.f, 0.f, 0.f, 0.f};

    h2 xq[4][4];   // [q][k-pair] packed f16 pairs (16 VGPR)
    const f16* wsrc = wstream + CHUNK_EL + wv*512 + lane*8;   // chunk 1 base
    const f16* x2base = x2g + ((size_t)(t*64 + wv*16 + lr) << 9) + kg*8;
    const int nodel4 = (wv*16 + lr) * 4;

    for (int vb = 0; vb < 4; ++vb) {
        // issue x2 refresh (4 dwordx4); drained by this body's vmcnt(0)
        {
            const f16* xb = x2base + vb*32;
            uint4 h0 = *(const uint4*)(xb);
            uint4 h1 = *(const uint4*)(xb + 128);
            uint4 h2v = *(const uint4*)(xb + 256);
            uint4 h3 = *(const uint4*)(xb + 384);
            xq[0][0]=bc(h0.x); xq[0][1]=bc(h0.y); xq[0][2]=bc(h0.z); xq[0][3]=bc(h0.w);
            xq[1][0]=bc(h1.x); xq[1][1]=bc(h1.y); xq[1][2]=bc(h1.z); xq[1][3]=bc(h1.w);
            xq[2][0]=bc(h2v.x); xq[2][1]=bc(h2v.y); xq[2][2]=bc(h2v.z); xq[2][3]=bc(h2v.w);
            xq[3][0]=bc(h3.x); xq[3][1]=bc(h3.y); xq[3][2]=bc(h3.z); xq[3][3]=bc(h3.w);
        }
        for (int u2b = 0; u2b < 32; u2b += 2) {
            #pragma unroll
            for (int uu = 0; uu < 2; ++uu) {       // LDS buffer index (static)
                const int u2 = u2b + uu;
                const int c  = vb*32 + u2;

                // wait for chunk c (staged one body ago; latency hidden), sync
                asm volatile("s_waitcnt vmcnt(0)" ::: "memory");
                __builtin_amdgcn_s_barrier();
                __builtin_amdgcn_sched_barrier(0);

                // stage chunk c+1 into buf[uu^1] (after barrier: race-free)
                if (c < 127) {
                    f16* dc = wlds + (uu^1)*CHUNK_EL + wv*512;
                    #pragma unroll
                    for (int r = 0; r < 5; ++r)
                        gl_lds16(wsrc + r*2048, dc + r*2048 + lane*8);
                }
                wsrc += CHUNK_EL;

                // x1 broadcasts (packed f16 pairs via v_perm)
                const uint2 h1 = *(const uint2*)(x1lds + u2*256 + nodel4);
                const h2 ps1 = bc(__builtin_amdgcn_perm(h1.x, h1.x, 0x01000100u));
                h2 pv[3];
                pv[0] = bc(__builtin_amdgcn_perm(h1.x, h1.x, 0x03020302u));
                pv[1] = bc(__builtin_amdgcn_perm(h1.y, h1.y, 0x01000100u));
                pv[2] = bc(__builtin_amdgcn_perm(h1.y, h1.y, 0x03020302u));

                // ---- A-gen: 11 fragments, computed once, used by 4 ct ----
                F8 f0, f1, fa[3], fb[3], fc[3];
                #pragma unroll
                for (int j = 0; j < 4; ++j) {
                    f0.h[j] = ps1 * xq[0][j];
                    h2 d = pv[0] * xq[1][j];
                    d = __builtin_elementwise_fma(pv[1], xq[2][j], d);
                    f1.h[j] = __builtin_elementwise_fma(pv[2], xq[3][j], d);
                }
                #pragma unroll
                for (int k = 0; k < 3; ++k) {
                    const int k1 = (k+1) % 3, k2 = (k+2) % 3;
                    #pragma unroll
                    for (int j = 0; j < 4; ++j) {
                        fa[k].h[j] = ps1   * xq[1+k][j];
                        fb[k].h[j] = pv[k] * xq[0][j];
                        h2 tx = pv[k1] * xq[1+k2][j];
                        fc[k].h[j] = __builtin_elementwise_fma(-pv[k2], xq[1+k1][j], tx);
                    }
                }

                // ---- per col-tile: 5 B-frags + 11 MFMA ----
                const f16* wb = wlds + uu*CHUNK_EL;
                #pragma unroll
                for (int ct = 0; ct < 4; ++ct) {
                    f16x8 b0 = *(const f16x8*)(wb +    0 + boff[ct]);
                    f16x8 b1 = *(const f16x8*)(wb + 2048 + boff[ct]);
                    f16x8 b2 = *(const f16x8*)(wb + 4096 + boff[ct]);
                    f16x8 b3 = *(const f16x8*)(wb + 6144 + boff[ct]);
                    f16x8 b4 = *(const f16x8*)(wb + 8192 + boff[ct]);
                    acc[ct][0] = __builtin_amdgcn_mfma_f32_16x16x32_f16(f0.v, b0, acc[ct][0], 0,0,0);
                    acc[ct][0] = __builtin_amdgcn_mfma_f32_16x16x32_f16(f1.v, b1, acc[ct][0], 0,0,0);
                    #pragma unroll
                    for (int k = 0; k < 3; ++k) {
                        acc[ct][1+k] = __builtin_amdgcn_mfma_f32_16x16x32_f16(fa[k].v, b2, acc[ct][1+k], 0,0,0);
                        acc[ct][1+k] = __builtin_amdgcn_mfma_f32_16x16x32_f16(fb[k].v, b3, acc[ct][1+k], 0,0,0);
                        acc[ct][1+k] = __builtin_amdgcn_mfma_f32_16x16x32_f16(fc[k].v, b4, acc[ct][1+k], 0,0,0);
                    }
                }
            }
        }
    }

    // epilogue: accumulate u-section partials into d_out (4 contributors/elem)
    #pragma unroll
    for (int ct = 0; ct < 4; ++ct) {
        const int w = whalf*64 + ct*16 + lr;
        #pragma unroll
        for (int j = 0; j < 4; ++j) {
            const int n = t*64 + wv*16 + kg*4 + j;
            float* op = out + (size_t)n*512;
            unsafeAtomicAdd(op + w,             acc[ct][0][j]);
            unsafeAtomicAdd(op + 128 + w*3 + 0, acc[ct][1][j]);
            unsafeAtomicAdd(op + 128 + w*3 + 1, acc[ct][2][j]);
            unsafeAtomicAdd(op + 128 + w*3 + 2, acc[ct][3][j]);
        }
    }
}

extern "C" void kernel_launch(void* const* d_in, const int* in_sizes, int n_in,
                              void* d_out, int out_size, void* d_ws, size_t ws_size,
                              hipStream_t stream)
{
    const float* x1s = (const float*)d_in[0];
    const float* x1v = (const float*)d_in[1];
    const float* x2s = (const float*)d_in[2];
    const float* x2v = (const float*)d_in[3];
    const float* w0  = (const float*)d_in[4];
    const float* w1  = (const float*)d_in[5];
    const float* w2  = (const float*)d_in[6];
    const float* w3  = (const float*)d_in[7];
    const float* w4  = (const float*)d_in[8];

    f16* wtb = (f16*)d_ws;
    f16* x1g = (f16*)((char*)d_ws + WT_BYTES);
    f16* x2g = (f16*)((char*)d_ws + WT_BYTES + X1_BYTES);
    float* out = (float*)d_out;

    pack_w_kernel<<<640, 256, 0, stream>>>(w0, w1, w2, w3, w4, wtb);
    pack_x_kernel<<<2176, 256, 0, stream>>>(x1s, x1v, x2s, x2v, x1g, x2g);
    hipMemsetAsync(d_out, 0, (size_t)out_size*sizeof(float), stream);
    tp_main<<<512, 256, 0, stream>>>(wtb, x1g, x2g, out);
}